// Round 5
// baseline (805.970 us; speedup 1.0000x reference)
//
#include <hip/hip_runtime.h>
#include <hip/hip_bf16.h>

// TransducerJoint: h[b,t,u,:] = f[b,t,:] + g[b,u,:] when t<f_len[b] && u<g_len[b], else 0.
// B=16, T=256, U=96, H=512, fp32.
// Write-bound: 805 MB out vs ~11 MB in. Roofline ~128 us @ 6.3 TB/s.
//
// Round-1 lesson: 393K x 128-thread blocks (one 16B store per thread) ran at
// ~1 TB/s — per-workgroup fixed cost dominated. Now: one block per (b,t),
// 4096 blocks x 256 threads; f row held in registers, 48-iteration u-loop,
// nontemporal 16B stores (output is write-once streaming, >> L3).
// Round-4 fix: __builtin_nontemporal_store needs a clang native vector type,
// not HIP's float4 struct — use ext_vector_type(4).

#define TJ_B 16
#define TJ_T 256
#define TJ_U 96
#define TJ_H 512
#define TJ_H4 (TJ_H / 4)   // 128 vec4 per row

typedef float fx4 __attribute__((ext_vector_type(4)));

__global__ __launch_bounds__(256) void TransducerJoint_66915590472509_kernel(
    const fx4* __restrict__ f,      // (B, T, H/4)
    const fx4* __restrict__ g,      // (B, U, H/4)
    const int* __restrict__ f_len,  // (B,)
    const int* __restrict__ g_len,  // (B,)
    fx4* __restrict__ out)          // (B, T, U, H/4)
{
    const int bt = blockIdx.x;          // b*T + t   (grid = B*T = 4096)
    const int b  = bt >> 8;             // T = 256 (pow2)
    const int t  = bt & 255;

    const int h4    = threadIdx.x & (TJ_H4 - 1);  // 0..127
    const int uhalf = threadIdx.x >> 7;           // 0 or 1

    const int flen = f_len[b];
    const int glen = g_len[b];
    const bool tvalid = (t < flen);     // block-uniform

    // f row fragment: 1 vec4/thread, reused across all 96 u.
    fx4 fv = (fx4)0.f;
    if (tvalid) fv = f[(size_t)bt * TJ_H4 + h4];

    const fx4* gp = g + ((size_t)(b * TJ_U + uhalf)) * TJ_H4 + h4;
    fx4* op = out + ((size_t)bt * TJ_U + uhalf) * TJ_H4 + h4;

    #pragma unroll 8
    for (int u = uhalf; u < TJ_U; u += 2) {
        const fx4 gv = *gp;             // L2-resident (g = 3 MB total)
        const bool ok = tvalid && (u < glen);
        fx4 r = ok ? (fv + gv) : (fx4)0.f;
        __builtin_nontemporal_store(r, op);   // write-once stream, skip cache
        gp += 2 * TJ_H4;
        op += 2 * TJ_H4;
    }
}

extern "C" void kernel_launch(void* const* d_in, const int* in_sizes, int n_in,
                              void* d_out, int out_size, void* d_ws, size_t ws_size,
                              hipStream_t stream) {
    const fx4* f     = (const fx4*)d_in[0];
    const fx4* g     = (const fx4*)d_in[1];
    const int* f_len = (const int*)d_in[2];
    const int* g_len = (const int*)d_in[3];
    fx4*       out   = (fx4*)d_out;

    const int nblocks = TJ_B * TJ_T;    // 4096 blocks, one per (b,t) row
    TransducerJoint_66915590472509_kernel<<<nblocks, 256, 0, stream>>>(
        f, g, f_len, g_len, out);
}

// Round 7
// 794.092 us; speedup vs baseline: 1.0150x; 1.0150x over previous
//
#include <hip/hip_runtime.h>
#include <hip/hip_bf16.h>

// TransducerJoint: h[b,t,u,:] = f[b,t,:] + g[b,u,:] when t<f_len[b] && u<g_len[b], else 0.
// B=16, T=256, U=96, H=512, fp32. Write-bound: 805 MB out, ~11 MB in.
// Roofline ~128 us @ 6.3 TB/s (harness's own 3GiB fill runs 6.29 TB/s on this buffer).
//
// Round-5 lesson: interleaving g-loads with the store stream ran at ~2.8 TB/s.
// Theory: vmcnt is a FIFO shared by loads AND stores; each load-use waitcnt
// must drain all older stores (slow under full write pressure), serializing
// the stream. Fix: ALL loads issue before ALL stores. Each block preloads the
// whole g[b] (24 fx4/thread x 512 threads = 192 KB) + 2 f rows into registers,
// then emits 48 pure coalesced stores/thread with zero intervening waits.

#define TJ_B 16
#define TJ_T 256
#define TJ_U 96
#define TJ_H4 128            // H/4 fx4 per row
#define TJ_TT 2              // t-rows per block
#define TJ_NTH 512           // threads per block
#define TJ_K ((TJ_U * TJ_H4) / TJ_NTH)   // 24 g-quads per thread

typedef float fx4 __attribute__((ext_vector_type(4)));

__global__ __launch_bounds__(TJ_NTH) void TransducerJoint_66915590472509_kernel(
    const fx4* __restrict__ f,      // (B, T, H/4)
    const fx4* __restrict__ g,      // (B, U, H/4)
    const int* __restrict__ f_len,  // (B,)
    const int* __restrict__ g_len,  // (B,)
    fx4* __restrict__ out)          // (B, T, U, H/4)
{
    const int bid = blockIdx.x;              // b*(T/TT) + tchunk
    const int b   = bid >> 7;                // T/TT = 128
    const int t0  = (bid & 127) * TJ_TT;
    const int i   = threadIdx.x;             // 0..511
    const int h4  = i & (TJ_H4 - 1);         // f fragment index (const across k)
    const int uu  = i >> 7;                  // base u offset: u_k = uu + 4k

    const int flen = f_len[b];
    const int glen = g_len[b];

    // ---- load phase: everything this block needs, BEFORE any store ----
    fx4 fr[TJ_TT];
    #pragma unroll
    for (int tt = 0; tt < TJ_TT; ++tt)
        fr[tt] = f[(size_t)(b * TJ_T + t0 + tt) * TJ_H4 + h4];   // always in-bounds

    fx4 gr[TJ_K];
    const fx4* gb = g + (size_t)b * (TJ_U * TJ_H4);
    #pragma unroll
    for (int k = 0; k < TJ_K; ++k)
        gr[k] = gb[i + TJ_NTH * k];          // whole g[b], wave-coalesced

    // ---- pure store phase: no loads -> load-waits never drain stores ----
    #pragma unroll
    for (int tt = 0; tt < TJ_TT; ++tt) {
        const int t = t0 + tt;
        const bool tok = (t < flen);         // block-uniform
        const fx4 fv = fr[tt];
        fx4* op = out + (size_t)(b * TJ_T + t) * (TJ_U * TJ_H4) + i;
        #pragma unroll
        for (int k = 0; k < TJ_K; ++k) {
            const bool ok = tok && ((uu + 4 * k) < glen);
            op[TJ_NTH * k] = ok ? (fv + gr[k]) : (fx4)0.f;
        }
    }
}

extern "C" void kernel_launch(void* const* d_in, const int* in_sizes, int n_in,
                              void* d_out, int out_size, void* d_ws, size_t ws_size,
                              hipStream_t stream) {
    const fx4* f     = (const fx4*)d_in[0];
    const fx4* g     = (const fx4*)d_in[1];
    const int* f_len = (const int*)d_in[2];
    const int* g_len = (const int*)d_in[3];
    fx4*       out   = (fx4*)d_out;

    const int nblocks = TJ_B * (TJ_T / TJ_TT);   // 2048
    TransducerJoint_66915590472509_kernel<<<nblocks, TJ_NTH, 0, stream>>>(
        f, g, f_len, g_len, out);
}